// Round 5
// baseline (1368.676 us; speedup 1.0000x reference)
//
#include <hip/hip_runtime.h>

#define GLOBAL_AS __attribute__((address_space(1)))
#define LDS_AS    __attribute__((address_space(3)))

typedef __bf16 bf16x8 __attribute__((ext_vector_type(8)));
typedef float  floatx4 __attribute__((ext_vector_type(4)));
typedef unsigned short ushort8 __attribute__((ext_vector_type(8)));

static constexpr int M_BATCH = 4096;
static constexpr int NPTS    = 512;
static constexpr int EMB     = 2048;
static constexpr int F0      = 1023;     // 2*NPTS-1
static constexpr int F0P     = 1024;     // padded feature count, K multiple of 64
static constexpr int K0      = 9 * F0P;  // 9216
static constexpr int K12     = 9 * EMB;  // 18432

// ---- float -> bf16 round-to-nearest-even ----
__device__ __forceinline__ unsigned short f2bf(float f) {
    unsigned int u = __float_as_uint(f);
    u += 0x7fffu + ((u >> 16) & 1u);
    return (unsigned short)(u >> 16);
}

// ---- relu + 8 cubic B-spline bases, mirroring the reference recursion ----
__device__ __forceinline__ void kan_phi(float x, float* v) {
    float g[12];
    #pragma unroll
    for (int i = 0; i < 12; ++i) g[i] = (float)(i - 3) * 0.4f - 1.0f;
    float b[11];
    #pragma unroll
    for (int i = 0; i < 11; ++i) b[i] = (x >= g[i] && x < g[i + 1]) ? 1.0f : 0.0f;
    #pragma unroll
    for (int k = 1; k <= 3; ++k) {
        #pragma unroll
        for (int i = 0; i + k < 11; ++i) {
            float left  = (x - g[i]) / (g[i + k] - g[i]);
            float right = (g[i + k + 1] - x) / (g[i + k + 1] - g[i + 1]);
            b[i] = left * b[i] + right * b[i + 1];
        }
    }
    v[0] = x > 0.0f ? x : 0.0f;
    #pragma unroll
    for (int i = 0; i < 8; ++i) v[1 + i] = b[i];
}

// ---- expand: one block per row n.
//      MODE 1: gather interleaved KAN input from xs (p0) / ys (p1).
//      MODE 0: x = p0[i] + p1[i]  (fused split-K=2 reduction of the
//              previous GEMM's partials).
//      LDS image laid out exactly as the global row [j*FP + f], flat
//      ushort8 copy-out (16B/lane both sides). ----
template<int FP, int MODE>
__global__ __launch_bounds__(256)
void expand_kernel(const float* __restrict__ p0,
                   const float* __restrict__ p1,
                   unsigned short* __restrict__ phi,
                   int F) {
    __shared__ __align__(16) unsigned short ebuf[9 * FP];
    const int n = blockIdx.x;
    const int tid = threadIdx.x;

    for (int f = tid; f < FP; f += 256) {
        bool valid = f < F;
        float x;
        if (MODE == 1) {
            // f even: xs[n, f>>1]; f odd: ys[n, f>>1]; f==1022 -> xs[n,511]
            const float* src = (f & 1) ? p1 : p0;
            x = valid ? src[(size_t)n * NPTS + (f >> 1)] : 0.0f;
        } else {
            size_t idx = (size_t)n * F + f;
            x = valid ? (p0[idx] + p1[idx]) : 0.0f;
        }
        float v[9];
        kan_phi(x, v);
        #pragma unroll
        for (int j = 0; j < 9; ++j)
            ebuf[j * FP + f] = valid ? f2bf(v[j]) : (unsigned short)0;
    }
    __syncthreads();

    unsigned short* dst = phi + (size_t)n * (size_t)(9 * FP);
    for (int t = tid; t < (9 * FP) / 8; t += 256)
        *reinterpret_cast<ushort8*>(dst + t * 8) =
            *reinterpret_cast<const ushort8*>(ebuf + t * 8);
}

// ---- pack W^T: one block per output row o. Coalesced float4 reads of sw,
//      LDS transpose with +8 pad, per-j ushort8 copy-out. ----
template<int FP>
__global__ __launch_bounds__(256)
void pack_w_kernel(const float* __restrict__ bw,
                   const float* __restrict__ sw,
                   const float* __restrict__ sc,
                   unsigned short* __restrict__ wt,
                   int F) {
    constexpr int FPP = FP + 8;
    __shared__ __align__(16) unsigned short wbuf[9 * FPP];
    __shared__ float scb[FP];
    const int o = blockIdx.x;
    const int tid = threadIdx.x;

    for (int f = tid; f < FP; f += 256) {
        bool valid = f < F;
        size_t s = (size_t)o * F + f;
        scb[f] = valid ? sc[s] : 0.0f;
        wbuf[0 * FPP + f] = valid ? f2bf(bw[s]) : (unsigned short)0;
        if (!valid) {
            #pragma unroll
            for (int j = 1; j < 9; ++j) wbuf[j * FPP + f] = 0;
        }
    }
    __syncthreads();

    const float4* sw4 = reinterpret_cast<const float4*>(sw + (size_t)o * F * 8);
    const int n4 = 2 * F;
    for (int t = tid; t < n4; t += 256) {
        float4 v = sw4[t];
        int flat = t * 4;
        #pragma unroll
        for (int c = 0; c < 4; ++c) {
            int fl = flat + c;
            int f = fl >> 3;
            int j = (fl & 7) + 1;
            float x = (c == 0) ? v.x : (c == 1) ? v.y : (c == 2) ? v.z : v.w;
            wbuf[j * FPP + f] = f2bf(x * scb[f]);
        }
    }
    __syncthreads();

    unsigned short* dst = wt + (size_t)o * (size_t)(9 * FP);
    #pragma unroll
    for (int j = 0; j < 9; ++j)
        for (int t = tid; t < FP / 8; t += 256)
            *reinterpret_cast<ushort8*>(dst + (size_t)j * FP + t * 8) =
                *reinterpret_cast<const ushort8*>(wbuf + j * FPP + t * 8);
}

// ---- bf16 GEMM: Cpart[z] = A(MxK) * B^T(NxK) over k-slice z. 128x128 tile,
//      BK=64, global_load_lds width 16, XOR-swizzled LDS. Split-K via
//      blockIdx.z; each slice writes its own partial buffer with PLAIN
//      stores (no atomics, no pre-zeroing). ----
__global__ __launch_bounds__(256, 2)
void gemm_bt_kernel(const unsigned short* __restrict__ A,
                    const unsigned short* __restrict__ B,
                    float* __restrict__ C,
                    int M, int N, int K, int kchunk) {
    __shared__ __align__(16) unsigned short Alds[128 * 64];
    __shared__ __align__(16) unsigned short Blds[128 * 64];

    const int tid  = threadIdx.x;
    const int wave = tid >> 6;
    const int lane = tid & 63;
    const int bm = blockIdx.y;
    const int bn = blockIdx.x;
    const int wm = (wave >> 1) * 64;
    const int wn = (wave & 1) * 64;
    const int kbase = blockIdx.z * kchunk;
    float* Cz = C + (size_t)blockIdx.z * (size_t)M * N;

    floatx4 zero = {0.f, 0.f, 0.f, 0.f};
    floatx4 acc[4][4];
    #pragma unroll
    for (int i = 0; i < 4; ++i)
        #pragma unroll
        for (int j = 0; j < 4; ++j)
            acc[i][j] = zero;

    int srow[4], scol[4];
    #pragma unroll
    for (int r = 0; r < 4; ++r) {
        int q = (r * 4 + wave) * 64 + lane;
        int row = q >> 3;
        int p = q & 7;
        srow[r] = row;
        scol[r] = (p ^ (row & 7)) * 8;
    }

    const unsigned short* Ab = A + (size_t)bm * 128 * K;
    const unsigned short* Bb = B + (size_t)bn * 128 * K;

    const int fr = lane & 15;
    const int fq = lane >> 4;

    for (int k0 = kbase; k0 < kbase + kchunk; k0 += 64) {
        #pragma unroll
        for (int r = 0; r < 4; ++r) {
            __builtin_amdgcn_global_load_lds(
                (const GLOBAL_AS void*)(Ab + (size_t)srow[r] * K + (k0 + scol[r])),
                (LDS_AS void*)(Alds + (r * 4 + wave) * 512),
                16, 0, 0);
        }
        #pragma unroll
        for (int r = 0; r < 4; ++r) {
            __builtin_amdgcn_global_load_lds(
                (const GLOBAL_AS void*)(Bb + (size_t)srow[r] * K + (k0 + scol[r])),
                (LDS_AS void*)(Blds + (r * 4 + wave) * 512),
                16, 0, 0);
        }
        __syncthreads();

        #pragma unroll
        for (int ks = 0; ks < 2; ++ks) {
            bf16x8 av[4], bv[4];
            #pragma unroll
            for (int mt = 0; mt < 4; ++mt) {
                int row = wm + mt * 16 + fr;
                int c   = ks * 4 + fq;
                int off = row * 64 + ((c ^ (row & 7)) * 8);
                av[mt] = *reinterpret_cast<const bf16x8*>(&Alds[off]);
            }
            #pragma unroll
            for (int nt = 0; nt < 4; ++nt) {
                int row = wn + nt * 16 + fr;
                int c   = ks * 4 + fq;
                int off = row * 64 + ((c ^ (row & 7)) * 8);
                bv[nt] = *reinterpret_cast<const bf16x8*>(&Blds[off]);
            }
            #pragma unroll
            for (int mt = 0; mt < 4; ++mt)
                #pragma unroll
                for (int nt = 0; nt < 4; ++nt)
                    acc[mt][nt] = __builtin_amdgcn_mfma_f32_16x16x32_bf16(
                        av[mt], bv[nt], acc[mt][nt], 0, 0, 0);
        }
        __syncthreads();
    }

    // epilogue: C/D layout col = lane&15, row = (lane>>4)*4 + reg
    const int rq = fq * 4;
    #pragma unroll
    for (int mt = 0; mt < 4; ++mt) {
        #pragma unroll
        for (int nt = 0; nt < 4; ++nt) {
            #pragma unroll
            for (int r = 0; r < 4; ++r) {
                int gr = bm * 128 + wm + mt * 16 + rq + r;
                int gc = bn * 128 + wn + nt * 16 + fr;
                Cz[(size_t)gr * N + gc] = acc[mt][nt][r];
            }
        }
    }
}

// ---- layer-2 fixup: out = sum of 8 k-slice partials ----
__global__ void add8_kernel(const float* __restrict__ p,
                            float* __restrict__ out, int n4, int slice4) {
    int i = blockIdx.x * blockDim.x + threadIdx.x;
    if (i >= n4) return;
    const float4* p4 = reinterpret_cast<const float4*>(p);
    float4 s = p4[i];
    #pragma unroll
    for (int z = 1; z < 8; ++z) {
        float4 v = p4[(size_t)z * slice4 + i];
        s.x += v.x; s.y += v.y; s.z += v.z; s.w += v.w;
    }
    reinterpret_cast<float4*>(out)[i] = s;
}

extern "C" void kernel_launch(void* const* d_in, const int* in_sizes, int n_in,
                              void* d_out, int out_size, void* d_ws, size_t ws_size,
                              hipStream_t stream) {
    const float* xs  = (const float*)d_in[0];
    const float* ys  = (const float*)d_in[1];
    const float* bw0 = (const float*)d_in[2];
    const float* sw0 = (const float*)d_in[3];
    const float* sc0 = (const float*)d_in[4];
    const float* bw1 = (const float*)d_in[5];
    const float* sw1 = (const float*)d_in[6];
    const float* sc1 = (const float*)d_in[7];
    const float* bw2 = (const float*)d_in[8];
    const float* sw2 = (const float*)d_in[9];
    const float* sc2 = (const float*)d_in[10];

    // workspace: Phi 151.0M | Wt 75.5M | Cpart 67.1M (reused per layer)
    char* ws = (char*)d_ws;
    unsigned short* Phi = (unsigned short*)ws;
    unsigned short* Wt  = (unsigned short*)(ws + 150994944);
    float* Cpart = (float*)(ws + 150994944 + 75497472);
    float* out = (float*)d_out;
    (void)ws_size; (void)in_sizes; (void)n_in; (void)out_size;

    const int T = 256;
    const size_t MN = (size_t)M_BATCH * EMB;   // partial slice size for L0/L1

    // ---- layer 0: 4096 x 9216 x 2048, split-K=2 -> 2 partial slices ----
    expand_kernel<F0P, 1><<<M_BATCH, T, 0, stream>>>(xs, ys, Phi, F0);
    pack_w_kernel<F0P><<<EMB, T, 0, stream>>>(bw0, sw0, sc0, Wt, F0);
    gemm_bt_kernel<<<dim3(16, 32, 2), T, 0, stream>>>(Phi, Wt, Cpart, M_BATCH, EMB, K0, K0 / 2);

    // ---- layer 1: expand fuses p0+p1; gemm overwrites Cpart (stream-safe) ----
    expand_kernel<EMB, 0><<<M_BATCH, T, 0, stream>>>(Cpart, Cpart + MN, Phi, EMB);
    pack_w_kernel<EMB><<<EMB, T, 0, stream>>>(bw1, sw1, sc1, Wt, EMB);
    gemm_bt_kernel<<<dim3(16, 32, 2), T, 0, stream>>>(Phi, Wt, Cpart, M_BATCH, EMB, K12, K12 / 2);

    // ---- layer 2: 4096 x 18432 x 512, split-K=8 (1024 blocks, 36 iters) ----
    expand_kernel<EMB, 0><<<M_BATCH, T, 0, stream>>>(Cpart, Cpart + MN, Phi, EMB);
    pack_w_kernel<EMB><<<NPTS, T, 0, stream>>>(bw2, sw2, sc2, Wt, EMB);
    gemm_bt_kernel<<<dim3(4, 32, 8), T, 0, stream>>>(Phi, Wt, Cpart, M_BATCH, NPTS, K12, K12 / 8);
    add8_kernel<<<(M_BATCH * NPTS / 4 + T - 1) / T, T, 0, stream>>>(
        Cpart, out, M_BATCH * NPTS / 4, M_BATCH * NPTS / 4);
}

// Round 6
// 1319.462 us; speedup vs baseline: 1.0373x; 1.0373x over previous
//
#include <hip/hip_runtime.h>

#define GLOBAL_AS __attribute__((address_space(1)))
#define LDS_AS    __attribute__((address_space(3)))

typedef __bf16 bf16x8 __attribute__((ext_vector_type(8)));
typedef float  floatx4 __attribute__((ext_vector_type(4)));
typedef unsigned short ushort8 __attribute__((ext_vector_type(8)));

static constexpr int M_BATCH = 4096;
static constexpr int NPTS    = 512;
static constexpr int EMB     = 2048;
static constexpr int F0      = 1023;     // 2*NPTS-1
static constexpr int F0P     = 1024;     // padded feature count, K multiple of 64
static constexpr int K0      = 9 * F0P;  // 9216
static constexpr int K12     = 9 * EMB;  // 18432

// ---- float -> bf16 round-to-nearest-even ----
__device__ __forceinline__ unsigned short f2bf(float f) {
    unsigned int u = __float_as_uint(f);
    u += 0x7fffu + ((u >> 16) & 1u);
    return (unsigned short)(u >> 16);
}

// ---- relu + 8 cubic B-spline bases, mirroring the reference recursion ----
__device__ __forceinline__ void kan_phi(float x, float* v) {
    float g[12];
    #pragma unroll
    for (int i = 0; i < 12; ++i) g[i] = (float)(i - 3) * 0.4f - 1.0f;
    float b[11];
    #pragma unroll
    for (int i = 0; i < 11; ++i) b[i] = (x >= g[i] && x < g[i + 1]) ? 1.0f : 0.0f;
    #pragma unroll
    for (int k = 1; k <= 3; ++k) {
        #pragma unroll
        for (int i = 0; i + k < 11; ++i) {
            float left  = (x - g[i]) / (g[i + k] - g[i]);
            float right = (g[i + k + 1] - x) / (g[i + k + 1] - g[i + 1]);
            b[i] = left * b[i] + right * b[i + 1];
        }
    }
    v[0] = x > 0.0f ? x : 0.0f;
    #pragma unroll
    for (int i = 0; i < 8; ++i) v[1 + i] = b[i];
}

// ---- fused aux: blocks [0, Nrows) expand activation rows; blocks
//      [Nrows, Nrows+O) pack weight rows. Both write basis-major K layout
//      [j*FP + f] matching the GEMM.
//      expand: ZERO LDS, no barriers — thread t covers feature base+t,
//        9 scalar ushort stores each coalescing to 128 B/wave segments.
//      pack: coalesced float4 sw reads -> 5 KB LDS transpose (2-way banks,
//        free) -> ushort8 copy-out at 512 B/wave/instr. ----
template<int FP, int MODE>
__global__ __launch_bounds__(256)
void aux_kernel(const float* __restrict__ p0,
                const float* __restrict__ p1,
                unsigned short* __restrict__ phi,
                int F, int Nrows,
                const float* __restrict__ bw,
                const float* __restrict__ sw,
                const float* __restrict__ sc,
                unsigned short* __restrict__ wt) {
    __shared__ __align__(16) unsigned short lds[8 * 264];
    __shared__ float scb[256];
    const int tid = threadIdx.x;

    if ((int)blockIdx.x < Nrows) {
        // ---------- expand row n ----------
        const int n = blockIdx.x;
        unsigned short* dst = phi + (size_t)n * (size_t)(9 * FP);
        for (int base = 0; base < FP; base += 256) {
            int f = base + tid;
            bool valid = f < F;
            float x;
            if (MODE == 1) {
                // f even: xs[n, f>>1]; f odd: ys[n, f>>1]
                const float* src = (f & 1) ? p1 : p0;
                x = valid ? src[(size_t)n * NPTS + (f >> 1)] : 0.0f;
            } else {
                size_t idx = (size_t)n * F + f;
                x = valid ? (p0[idx] + p1[idx]) : 0.0f;
            }
            float v[9];
            kan_phi(x, v);
            #pragma unroll
            for (int j = 0; j < 9; ++j)
                dst[j * FP + f] = valid ? f2bf(v[j]) : (unsigned short)0;
        }
    } else {
        // ---------- pack weight row o ----------
        const int o = blockIdx.x - Nrows;
        unsigned short* dst = wt + (size_t)o * (size_t)(9 * FP);
        const float4* swr = reinterpret_cast<const float4*>(sw + (size_t)o * F * 8);
        const int F4 = 2 * F;   // float4 count in the sw row

        for (int base = 0; base < FP; base += 256) {
            int f = base + tid;
            bool valid = f < F;
            size_t s = (size_t)o * F + f;
            // slot 0 (base_w): both sides coalesced, no staging needed
            dst[f] = valid ? f2bf(bw[s]) : (unsigned short)0;
            scb[tid] = valid ? sc[s] : 0.0f;
            __syncthreads();

            // read 256 features x 8 = 512 float4s, scatter bf16 into LDS
            #pragma unroll
            for (int r = 0; r < 2; ++r) {
                int t4 = r * 256 + tid;          // 0..511
                int g4 = base * 2 + t4;          // global float4 index
                float4 v = (g4 < F4) ? swr[g4] : float4{0.f, 0.f, 0.f, 0.f};
                int flat = t4 * 4;
                #pragma unroll
                for (int c = 0; c < 4; ++c) {
                    int fl = flat + c;
                    int fL = fl >> 3;            // local feature 0..255
                    int j  = fl & 7;             // spline slot
                    float xv = (c == 0) ? v.x : (c == 1) ? v.y : (c == 2) ? v.z : v.w;
                    lds[j * 264 + fL] = f2bf(xv * scb[fL]);
                }
            }
            __syncthreads();

            // copy out: thread t -> j = t>>5, f8 = (t&31)*8 (512 B/wave/instr)
            {
                int j  = tid >> 5;
                int f8 = (tid & 31) * 8;
                ushort8 u = *reinterpret_cast<const ushort8*>(&lds[j * 264 + f8]);
                *reinterpret_cast<ushort8*>(dst + (size_t)(j + 1) * FP + base + f8) = u;
            }
            __syncthreads();
        }
    }
}

// ---- bf16 GEMM: Cpart[z] = A(MxK) * B^T(NxK) over k-slice z. 128x128 tile,
//      BK=64, global_load_lds width 16, XOR-swizzled LDS. Split-K via
//      blockIdx.z; plain stores into per-slice partials. (R5-verified.) ----
__global__ __launch_bounds__(256, 2)
void gemm_bt_kernel(const unsigned short* __restrict__ A,
                    const unsigned short* __restrict__ B,
                    float* __restrict__ C,
                    int M, int N, int K, int kchunk) {
    __shared__ __align__(16) unsigned short Alds[128 * 64];
    __shared__ __align__(16) unsigned short Blds[128 * 64];

    const int tid  = threadIdx.x;
    const int wave = tid >> 6;
    const int lane = tid & 63;
    const int bm = blockIdx.y;
    const int bn = blockIdx.x;
    const int wm = (wave >> 1) * 64;
    const int wn = (wave & 1) * 64;
    const int kbase = blockIdx.z * kchunk;
    float* Cz = C + (size_t)blockIdx.z * (size_t)M * N;

    floatx4 zero = {0.f, 0.f, 0.f, 0.f};
    floatx4 acc[4][4];
    #pragma unroll
    for (int i = 0; i < 4; ++i)
        #pragma unroll
        for (int j = 0; j < 4; ++j)
            acc[i][j] = zero;

    int srow[4], scol[4];
    #pragma unroll
    for (int r = 0; r < 4; ++r) {
        int q = (r * 4 + wave) * 64 + lane;
        int row = q >> 3;
        int p = q & 7;
        srow[r] = row;
        scol[r] = (p ^ (row & 7)) * 8;
    }

    const unsigned short* Ab = A + (size_t)bm * 128 * K;
    const unsigned short* Bb = B + (size_t)bn * 128 * K;

    const int fr = lane & 15;
    const int fq = lane >> 4;

    for (int k0 = kbase; k0 < kbase + kchunk; k0 += 64) {
        #pragma unroll
        for (int r = 0; r < 4; ++r) {
            __builtin_amdgcn_global_load_lds(
                (const GLOBAL_AS void*)(Ab + (size_t)srow[r] * K + (k0 + scol[r])),
                (LDS_AS void*)(Alds + (r * 4 + wave) * 512),
                16, 0, 0);
        }
        #pragma unroll
        for (int r = 0; r < 4; ++r) {
            __builtin_amdgcn_global_load_lds(
                (const GLOBAL_AS void*)(Bb + (size_t)srow[r] * K + (k0 + scol[r])),
                (LDS_AS void*)(Blds + (r * 4 + wave) * 512),
                16, 0, 0);
        }
        __syncthreads();

        #pragma unroll
        for (int ks = 0; ks < 2; ++ks) {
            bf16x8 av[4], bv[4];
            #pragma unroll
            for (int mt = 0; mt < 4; ++mt) {
                int row = wm + mt * 16 + fr;
                int c   = ks * 4 + fq;
                int off = row * 64 + ((c ^ (row & 7)) * 8);
                av[mt] = *reinterpret_cast<const bf16x8*>(&Alds[off]);
            }
            #pragma unroll
            for (int nt = 0; nt < 4; ++nt) {
                int row = wn + nt * 16 + fr;
                int c   = ks * 4 + fq;
                int off = row * 64 + ((c ^ (row & 7)) * 8);
                bv[nt] = *reinterpret_cast<const bf16x8*>(&Blds[off]);
            }
            #pragma unroll
            for (int mt = 0; mt < 4; ++mt)
                #pragma unroll
                for (int nt = 0; nt < 4; ++nt)
                    acc[mt][nt] = __builtin_amdgcn_mfma_f32_16x16x32_bf16(
                        av[mt], bv[nt], acc[mt][nt], 0, 0, 0);
        }
        __syncthreads();
    }

    const int rq = fq * 4;
    #pragma unroll
    for (int mt = 0; mt < 4; ++mt) {
        #pragma unroll
        for (int nt = 0; nt < 4; ++nt) {
            #pragma unroll
            for (int r = 0; r < 4; ++r) {
                int gr = bm * 128 + wm + mt * 16 + rq + r;
                int gc = bn * 128 + wn + nt * 16 + fr;
                Cz[(size_t)gr * N + gc] = acc[mt][nt][r];
            }
        }
    }
}

// ---- layer-2 fixup: out = sum of 8 k-slice partials ----
__global__ void add8_kernel(const float* __restrict__ p,
                            float* __restrict__ out, int n4, int slice4) {
    int i = blockIdx.x * blockDim.x + threadIdx.x;
    if (i >= n4) return;
    const float4* p4 = reinterpret_cast<const float4*>(p);
    float4 s = p4[i];
    #pragma unroll
    for (int z = 1; z < 8; ++z) {
        float4 v = p4[(size_t)z * slice4 + i];
        s.x += v.x; s.y += v.y; s.z += v.z; s.w += v.w;
    }
    reinterpret_cast<float4*>(out)[i] = s;
}

extern "C" void kernel_launch(void* const* d_in, const int* in_sizes, int n_in,
                              void* d_out, int out_size, void* d_ws, size_t ws_size,
                              hipStream_t stream) {
    const float* xs  = (const float*)d_in[0];
    const float* ys  = (const float*)d_in[1];
    const float* bw0 = (const float*)d_in[2];
    const float* sw0 = (const float*)d_in[3];
    const float* sc0 = (const float*)d_in[4];
    const float* bw1 = (const float*)d_in[5];
    const float* sw1 = (const float*)d_in[6];
    const float* sc1 = (const float*)d_in[7];
    const float* bw2 = (const float*)d_in[8];
    const float* sw2 = (const float*)d_in[9];
    const float* sc2 = (const float*)d_in[10];

    // workspace: Phi 151.0M | Wt 75.5M | Cpart 67.1M (reused per layer)
    char* ws = (char*)d_ws;
    unsigned short* Phi = (unsigned short*)ws;
    unsigned short* Wt  = (unsigned short*)(ws + 150994944);
    float* Cpart = (float*)(ws + 150994944 + 75497472);
    float* out = (float*)d_out;
    (void)ws_size; (void)in_sizes; (void)n_in; (void)out_size;

    const int T = 256;
    const size_t MN = (size_t)M_BATCH * EMB;   // partial slice size for L0/L1

    // ---- layer 0: 4096 x 9216 x 2048, split-K=2 -> 2 partial slices ----
    aux_kernel<F0P, 1><<<M_BATCH + EMB, T, 0, stream>>>(
        xs, ys, Phi, F0, M_BATCH, bw0, sw0, sc0, Wt);
    gemm_bt_kernel<<<dim3(16, 32, 2), T, 0, stream>>>(Phi, Wt, Cpart, M_BATCH, EMB, K0, K0 / 2);

    // ---- layer 1: expand fuses p0+p1 partial reduction ----
    aux_kernel<EMB, 0><<<M_BATCH + EMB, T, 0, stream>>>(
        Cpart, Cpart + MN, Phi, EMB, M_BATCH, bw1, sw1, sc1, Wt);
    gemm_bt_kernel<<<dim3(16, 32, 2), T, 0, stream>>>(Phi, Wt, Cpart, M_BATCH, EMB, K12, K12 / 2);

    // ---- layer 2: 4096 x 18432 x 512, split-K=8 (1024 blocks, 36 iters) ----
    aux_kernel<EMB, 0><<<M_BATCH + NPTS, T, 0, stream>>>(
        Cpart, Cpart + MN, Phi, EMB, M_BATCH, bw2, sw2, sc2, Wt);
    gemm_bt_kernel<<<dim3(4, 32, 8), T, 0, stream>>>(Phi, Wt, Cpart, M_BATCH, NPTS, K12, K12 / 8);
    add8_kernel<<<(M_BATCH * NPTS / 4 + T - 1) / T, T, 0, stream>>>(
        Cpart, out, M_BATCH * NPTS / 4, M_BATCH * NPTS / 4);
}